// Round 5
// baseline (642.946 us; speedup 1.0000x reference)
//
#include <hip/hip_runtime.h>

// HAR LSTM: 16-lane chain-layer split, all-VALU cross-lane.
// Group of 16 lanes = one (chain, encoder, layer). lane = 4*quad + g:
// quad 0..2 = hidden unit, quad 3 = replica of unit 0 (never sourced: its
// weight slot is 0); g = gate row (i,f,g,o). Per step each lane computes ONE
// gate row: 8-FMA chain from 4 own-h sources {own, half_mirror, ror8, mirror}
// (direction-invariant DPP controls; h is quad-uniform so in-quad reversal is
// irrelevant) + 4 partner-layer sources (shfl_xor 32 + same mirrors), then one
// unified activation exp2+rcp (scales folded into weights), quad_perm act
// broadcast, c/h update (duplicated quad-wide). wi*x+bias precomputed per
// 16-step chunk into registers (l1 lanes hold pure bias) -> zero per-step
// selects. Wave = 2 chains x 2 layers; block = 3 e-waves; grid = 1024 ->
// 3072 waves = 3/SIMD even (4 blocks/CU). 1-step layer skew; 32-slot h1 ring;
// BN+ReLU+mean flush with lag 2.

#define T_LEN 2048
#define BATCH 1024
#define CHUNK 16
#define NCHUNK 128
#define NCH 2   // chains per block

#define CTL_HALF_MIRROR 0x141
#define CTL_MIRROR      0x140
#define CTL_ROR8        0x128
#define CTL_QP0         0x00
#define CTL_QP1         0x55
#define CTL_QP2         0xAA
#define CTL_QP3         0xFF

template<int CTRL>
__device__ __forceinline__ float dpp_f(float v) {
    const int i = __float_as_int(v);
    return __int_as_float(__builtin_amdgcn_update_dpp(i, i, CTRL, 0xF, 0xF, false));
}

__launch_bounds__(192, 3)
__global__ void har_lstm_kernel(
    const float* __restrict__ x,
    const float* __restrict__ Wi0, const float* __restrict__ Wh0,
    const float* __restrict__ bi0, const float* __restrict__ bh0,
    const float* __restrict__ Wi1, const float* __restrict__ Wh1,
    const float* __restrict__ bi1, const float* __restrict__ bh1,
    const float* __restrict__ bng, const float* __restrict__ bnb,
    const float* __restrict__ bnm, const float* __restrict__ bnv,
    float* __restrict__ out)
{
    __shared__ __align__(16) float lds_x[NCH * 64];        // [ci][t][x0,x1,x2,pad]
    __shared__ __align__(16) float lds_o[3 * NCH * 132];   // [(e,ci)][slot*4+u]
    __shared__ __align__(16) float lds_bn[T_LEN * 2];      // [t][sc,sh]
    __shared__ float lds_dump[192];

    const int lane = threadIdx.x;        // 0..63
    const int e    = threadIdx.y;        // 0..2
    const int tix  = e * 64 + lane;

    const int rowi = lane >> 4;          // 0..3: c0l0, c1l0, c0l1, c1l1
    const int L    = rowi >> 1;          // layer
    const int ci   = rowi & 1;           // chain within block
    const int quad = (lane >> 2) & 3;    // unit (3 = replica of 0)
    const int u    = (quad == 3) ? 0 : quad;
    const int g    = lane & 3;           // gate (i,f,g,o)
    const int row  = g * 3 + u;          // PyTorch gate-row index

    // ---- BN (scale, shift) table ----
    for (int idx = tix; idx < T_LEN; idx += 192) {
        const float sc = bng[idx] * rsqrtf(bnv[idx] + 1e-5f);
        lds_bn[2 * idx]     = sc;
        lds_bn[2 * idx + 1] = bnb[idx] - bnm[idx] * sc;
    }

    // ---- per-lane weights, activation pre-scales folded in ----
    const float LOG2E = 1.4426950408889634f;
    const float s  = (g == 2) ? (2.f * LOG2E) : (-LOG2E);   // tanh vs sigmoid
    const float AA = (g == 2) ? 1.f : 0.f;                  // act = AA + BA*rcp(1+exp2(pre))
    const float BA = (g == 2) ? -2.f : 1.f;
    const float* Wi = L ? Wi1 : Wi0;
    const float* Wh = L ? Wh1 : Wh0;
    const float* bi = L ? bi1 : bi0;
    const float* bh = L ? bh1 : bh0;

    float wir[3], whr[3];
    #pragma unroll
    for (int k = 0; k < 3; ++k) {
        wir[k] = s * Wi[e * 36 + row * 3 + k];
        whr[k] = s * Wh[e * 36 + row * 3 + k];
    }
    const float bs = s * (bi[e * 12 + row] + bh[e * 12 + row]);

    // source->quad map: own=quad, half_mirror=quad^1, ror8=quad^2, mirror=quad^3
    auto hw = [&](const float* w, int srcq) -> float {
        return (srcq == 3) ? 0.f : w[srcq];
    };
    const float whA = hw(whr, quad),   whM1 = hw(whr, quad ^ 1);
    const float whM2 = hw(whr, quad ^ 2), whM3 = hw(whr, quad ^ 3);
    const float wsA = L ? hw(wir, quad)     : 0.f;   // partner-layer (input) sources, l1 only
    const float ws1 = L ? hw(wir, quad ^ 1) : 0.f;
    const float ws2 = L ? hw(wir, quad ^ 2) : 0.f;
    const float ws3 = L ? hw(wir, quad ^ 3) : 0.f;
    const float wx0 = L ? 0.f : wir[0];              // x-projection weights, l0 only
    const float wx1 = L ? 0.f : wir[1];
    const float wx2 = L ? 0.f : wir[2];

    // ---- output routing ----
    const int n  = blockIdx.x * NCH + ci;
    const int b  = (n < BATCH) ? n : n - BATCH;
    const int cb = (n < BATCH) ? 0 : 3;
    const bool real = (L == 1) && (g == 0) && (quad < 3);
    float* wbase = real ? &lds_o[(e * NCH + ci) * 132 + u] : &lds_dump[tix];
    const int wmask = real ? -1 : 0;

    float h = 0.f, c = 0.f;
    float xp[CHUNK];

    auto stage = [&](int cnk) {
        if (tix < 24) {
            const int seg = tix & 3;
            const int r   = tix >> 2;    // 0..5
            const int ii  = r & 1;
            const int ch  = r >> 1;      // 0..2
            const int nn  = blockIdx.x * NCH + ii;
            const int bb  = (nn < BATCH) ? nn : nn - BATCH;
            const int cc  = (nn < BATCH) ? 0 : 3;
            const float4 v = *reinterpret_cast<const float4*>(
                x + ((size_t)(bb * 6 + cc + ch)) * T_LEN + cnk * CHUNK + seg * 4);
            float* d = &lds_x[ii * 64 + seg * 16 + ch];
            d[0] = v.x; d[4] = v.y; d[8] = v.z; d[12] = v.w;
        }
    };

    auto xproj = [&]() {
        #pragma unroll
        for (int tt = 0; tt < CHUNK; ++tt) {
            const float4 xv = *reinterpret_cast<const float4*>(&lds_x[ci * 64 + tt * 4]);
            xp[tt] = fmaf(wx0, xv.x, fmaf(wx1, xv.y, fmaf(wx2, xv.z, bs)));
        }
    };

    auto body = [&](int t, float xpv) {
        const float S  = __shfl_xor(h, 32);        // partner layer's h (one DS op)
        const float A1 = dpp_f<CTL_HALF_MIRROR>(h);
        const float A2 = dpp_f<CTL_ROR8>(h);
        const float A3 = dpp_f<CTL_MIRROR>(h);
        const float S1 = dpp_f<CTL_HALF_MIRROR>(S);
        const float S2 = dpp_f<CTL_ROR8>(S);
        const float S3 = dpp_f<CTL_MIRROR>(S);
        float pre = fmaf(whA, h, xpv);
        pre = fmaf(whM1, A1, pre);
        pre = fmaf(whM2, A2, pre);
        pre = fmaf(whM3, A3, pre);
        pre = fmaf(wsA, S,  pre);
        pre = fmaf(ws1, S1, pre);
        pre = fmaf(ws2, S2, pre);
        pre = fmaf(ws3, S3, pre);
        const float ev  = __builtin_amdgcn_exp2f(pre);
        const float r   = __builtin_amdgcn_rcpf(1.f + ev);
        const float act = fmaf(BA, r, AA);
        const float ai = dpp_f<CTL_QP0>(act);      // sigma(i) from lane g=0
        const float af = dpp_f<CTL_QP1>(act);
        const float ag = dpp_f<CTL_QP2>(act);      // tanh(g) from lane g=2
        const float ao = dpp_f<CTL_QP3>(act);
        c = fmaf(af, c, ai * ag);
        const float e2 = __builtin_amdgcn_exp2f(2.8853900817779268f * c);
        const float th = fmaf(-2.f, __builtin_amdgcn_rcpf(1.f + e2), 1.f);
        h = ao * th;
        wbase[(((t + 31) & 31) * 4) & wmask] = h;  // l1: h1(t-1) -> ring slot (t-1)&31
    };

    auto flush = [&](int f) {
        if (tix < 96) {
            const int tt = tix & 15;
            const int r  = tix >> 4;     // 0..5
            const int ii = r & 1;
            const int uu = r >> 1;       // 0..2
            const int nn = blockIdx.x * NCH + ii;
            const int bb = (nn < BATCH) ? nn : nn - BATCH;
            const int cc = (nn < BATCH) ? 0 : 3;
            const int t  = f * CHUNK + tt;
            const int slot = t & 31;
            const float sc = lds_bn[2 * t];
            const float sh = lds_bn[2 * t + 1];
            float acc = 0.f;
            #pragma unroll
            for (int ee = 0; ee < 3; ++ee)
                acc += fmaxf(0.f, fmaf(lds_o[(ee * NCH + ii) * 132 + slot * 4 + uu], sc, sh));
            out[((size_t)(bb * 6 + cc + uu)) * T_LEN + t] = acc * (1.f / 3.f);
        }
    };

    // ================= schedule =================
    stage(0);
    __syncthreads();
    xproj();

    body(0, xp[0]);
    if (L) { h = 0.f; c = 0.f; }        // discard layer-1's tau=-1 garbage
    #pragma unroll
    for (int tt = 1; tt < CHUNK; ++tt) body(tt, xp[tt]);

    #pragma unroll 1
    for (int cnk = 1; cnk < NCHUNK; ++cnk) {
        __syncthreads();
        stage(cnk);
        if (cnk >= 2) flush(cnk - 2);
        __syncthreads();
        xproj();
        const int tb = cnk * CHUNK;
        #pragma unroll
        for (int tt = 0; tt < CHUNK; ++tt) body(tb + tt, xp[tt]);
    }

    __syncthreads();
    flush(NCHUNK - 2);
    __syncthreads();
    body(T_LEN, bs);                    // layer-1 completes step T-1 (xp = pure bias)
    __syncthreads();
    flush(NCHUNK - 1);
}

extern "C" void kernel_launch(void* const* d_in, const int* in_sizes, int n_in,
                              void* d_out, int out_size, void* d_ws, size_t ws_size,
                              hipStream_t stream) {
    (void)in_sizes; (void)n_in; (void)out_size; (void)d_ws; (void)ws_size;
    const float* x   = (const float*)d_in[0];
    const float* Wi0 = (const float*)d_in[1];
    const float* Wh0 = (const float*)d_in[2];
    const float* bi0 = (const float*)d_in[3];
    const float* bh0 = (const float*)d_in[4];
    const float* Wi1 = (const float*)d_in[5];
    const float* Wh1 = (const float*)d_in[6];
    const float* bi1 = (const float*)d_in[7];
    const float* bh1 = (const float*)d_in[8];
    const float* bng = (const float*)d_in[9];
    const float* bnb = (const float*)d_in[10];
    const float* bnm = (const float*)d_in[11];
    const float* bnv = (const float*)d_in[12];

    har_lstm_kernel<<<dim3(1024), dim3(64, 3), 0, stream>>>(
        x, Wi0, Wh0, bi0, bh0, Wi1, Wh1, bi1, bh1, bng, bnb, bnm, bnv,
        (float*)d_out);
}

// Round 6
// 516.219 us; speedup vs baseline: 1.2455x; 1.2455x over previous
//
#include <hip/hip_runtime.h>

// HAR LSTM: 8-lane chain-layer split with ALL-DPP cross-lane exchange.
// 16-lane row = one chain: lanes [0..7] = layer0, [8..15] = layer1.
// Within an 8-half: pos = 2u+p (u=unit, p=gate-pair: p0={i,f}, p1={g,o});
// pos 6,7 duplicate unit 2 -> h layout per half = [h0,h0,h1,h1,h2,h2,h2,h2].
// Cross-lane per step (all VALU DPP, zero DS reads):
//   trio sources: own, P=qp[2,3,0,1], M=row_half_mirror, M2=P(M)
//   layer handoff: R=row_ror:8 (+P/M/M2 of R)
//   act-pair swap: qp[1,0,3,2]
// Per-lane source->unit map computed at init with keep-first dedup (weight 0
// for duplicate sources). x-projections + bias precomputed per 16-step chunk
// into registers (layer1 lanes: pure bias). Only per-step DS op = ring write
// (no in-step reader -> no lgkm wait on the dependence chain).
// Wave = 4 chains x 2 layers; block = 3 e-waves; grid 512 -> 1536 waves.

#define T_LEN 2048
#define BATCH 1024
#define CHUNK 16
#define NCHUNK 128
#define NCH 4

#define CTL_P    0x4E   // quad_perm [2,3,0,1]
#define CTL_SWAP 0xB1   // quad_perm [1,0,3,2]
#define CTL_HM   0x141  // row_half_mirror
#define CTL_ROR8 0x128  // row_ror:8

template<int CTRL>
__device__ __forceinline__ float dpp_f(float v) {
    const int i = __float_as_int(v);
    return __int_as_float(__builtin_amdgcn_update_dpp(i, i, CTRL, 0xF, 0xF, false));
}

__launch_bounds__(192, 2)
__global__ void har_lstm_kernel(
    const float* __restrict__ x,
    const float* __restrict__ Wi0, const float* __restrict__ Wh0,
    const float* __restrict__ bi0, const float* __restrict__ bh0,
    const float* __restrict__ Wi1, const float* __restrict__ Wh1,
    const float* __restrict__ bi1, const float* __restrict__ bh1,
    const float* __restrict__ bng, const float* __restrict__ bnb,
    const float* __restrict__ bnm, const float* __restrict__ bnv,
    float* __restrict__ out)
{
    __shared__ __align__(16) float lds_x[NCH * 68];     // [ci][t*4+ch], stride 68
    __shared__ __align__(16) float lds_o[36 * 34];      // [(e*4+ci)*3+u][slot(32)+2pad]
    __shared__ __align__(16) float lds_bn[T_LEN * 2];   // [t][sc,sh]
    __shared__ float lds_dump[192];

    const int lane = threadIdx.x;        // 0..63
    const int e    = threadIdx.y;        // 0..2
    const int tix  = e * 64 + lane;

    const int ci   = lane >> 4;          // chain in wave 0..3
    const int L    = (lane >> 3) & 1;    // layer
    const int pos  = lane & 7;
    const int u    = (pos >= 6) ? 2 : (pos >> 1);
    const int p    = pos & 1;

    // ---- BN (scale, shift) table ----
    for (int idx = tix; idx < T_LEN; idx += 192) {
        const float sc = bng[idx] * rsqrtf(bnv[idx] + 1e-5f);
        lds_bn[2 * idx]     = sc;
        lds_bn[2 * idx + 1] = bnb[idx] - bnm[idx] * sc;
    }

    // ---- per-lane weights ----
    const float LOG2E = 1.4426950408889634f;
    const int rowA = (p == 0) ? u : (6 + u);          // i_u or g_u
    const int rowB = (p == 0) ? (3 + u) : (9 + u);    // f_u or o_u
    const float sA = (p == 0) ? -LOG2E : 2.f * LOG2E;
    const float sB = -LOG2E;
    const float AA = (p == 0) ? 0.f : 1.f;            // act = AA + BA*rcp(1+exp2(pre))
    const float BA = (p == 0) ? 1.f : -2.f;
    const float* Wi = L ? Wi1 : Wi0;
    const float* Wh = L ? Wh1 : Wh0;
    const float* bi = L ? bi1 : bi0;
    const float* bh = L ? bh1 : bh0;

    // source -> unit map: own(pos), P(pos^2), M(7-pos), M2(7-(pos^2)); dedup keep-first
    auto unit_of = [](int q) -> int { return (q >= 6) ? 2 : (q >> 1); };
    int srcu[4] = { u, unit_of(pos ^ 2), unit_of(7 - pos), unit_of(7 - (pos ^ 2)) };
    float kw[4];
    {
        bool seen[3] = {false, false, false};
        #pragma unroll
        for (int s2 = 0; s2 < 4; ++s2) {
            if (!seen[srcu[s2]]) { seen[srcu[s2]] = true; kw[s2] = 1.f; }
            else kw[s2] = 0.f;
        }
    }
    float whA[4], whB[4], wrA[4], wrB[4];
    #pragma unroll
    for (int s2 = 0; s2 < 4; ++s2) {
        whA[s2] = kw[s2] * sA * Wh[e * 36 + rowA * 3 + srcu[s2]];
        whB[s2] = kw[s2] * sB * Wh[e * 36 + rowB * 3 + srcu[s2]];
        wrA[s2] = L ? kw[s2] * sA * Wi[e * 36 + rowA * 3 + srcu[s2]] : 0.f;
        wrB[s2] = L ? kw[s2] * sB * Wi[e * 36 + rowB * 3 + srcu[s2]] : 0.f;
    }
    const float wxA0 = L ? 0.f : sA * Wi[e * 36 + rowA * 3 + 0];
    const float wxA1 = L ? 0.f : sA * Wi[e * 36 + rowA * 3 + 1];
    const float wxA2 = L ? 0.f : sA * Wi[e * 36 + rowA * 3 + 2];
    const float wxB0 = L ? 0.f : sB * Wi[e * 36 + rowB * 3 + 0];
    const float wxB1 = L ? 0.f : sB * Wi[e * 36 + rowB * 3 + 1];
    const float wxB2 = L ? 0.f : sB * Wi[e * 36 + rowB * 3 + 2];
    const float bsA = sA * (bi[e * 12 + rowA] + bh[e * 12 + rowA]);
    const float bsB = sB * (bi[e * 12 + rowB] + bh[e * 12 + rowB]);

    // ---- output routing ----
    const int n  = blockIdx.x * NCH + ci;
    const int b  = (n < BATCH) ? n : n - BATCH;
    const int cb = (n < BATCH) ? 0 : 3;
    const bool real = (L == 1) && (p == 0) && (pos < 6);
    float* wbase = real ? &lds_o[((e * 4 + ci) * 3 + u) * 34] : &lds_dump[tix];
    const int wmask = real ? -1 : 0;

    float h = 0.f, c = 0.f;
    float xpA[CHUNK], xpB[CHUNK];

    auto stage = [&](int cnk) {
        if (tix < 48) {
            const int seg = tix & 3;
            const int r   = tix >> 2;    // 0..11
            const int ii  = r & 3;
            const int ch  = r >> 2;      // 0..2
            const int nn  = blockIdx.x * NCH + ii;
            const int bb  = (nn < BATCH) ? nn : nn - BATCH;
            const int cc  = (nn < BATCH) ? 0 : 3;
            const float4 v = *reinterpret_cast<const float4*>(
                x + ((size_t)(bb * 6 + cc + ch)) * T_LEN + cnk * CHUNK + seg * 4);
            float* d = &lds_x[ii * 68 + seg * 16 + ch];
            d[0] = v.x; d[4] = v.y; d[8] = v.z; d[12] = v.w;
        }
    };

    auto xproj = [&]() {
        #pragma unroll
        for (int tt = 0; tt < CHUNK; ++tt) {
            const float4 xv = *reinterpret_cast<const float4*>(&lds_x[ci * 68 + tt * 4]);
            xpA[tt] = fmaf(wxA0, xv.x, fmaf(wxA1, xv.y, fmaf(wxA2, xv.z, bsA)));
            xpB[tt] = fmaf(wxB0, xv.x, fmaf(wxB1, xv.y, fmaf(wxB2, xv.z, bsB)));
        }
    };

    auto body = [&](int t, float xa, float xb) {
        // all-VALU cross-lane exchange
        const float hP  = dpp_f<CTL_P>(h);
        const float hM  = dpp_f<CTL_HM>(h);
        const float hM2 = dpp_f<CTL_P>(hM);
        const float R   = dpp_f<CTL_ROR8>(h);   // partner layer, same pos
        const float RP  = dpp_f<CTL_P>(R);
        const float RM  = dpp_f<CTL_HM>(R);
        const float RM2 = dpp_f<CTL_P>(RM);
        float gA = fmaf(whA[0], h, xa);
        gA = fmaf(whA[1], hP, gA); gA = fmaf(whA[2], hM, gA); gA = fmaf(whA[3], hM2, gA);
        gA = fmaf(wrA[0], R, gA);  gA = fmaf(wrA[1], RP, gA);
        gA = fmaf(wrA[2], RM, gA); gA = fmaf(wrA[3], RM2, gA);
        float gB = fmaf(whB[0], h, xb);
        gB = fmaf(whB[1], hP, gB); gB = fmaf(whB[2], hM, gB); gB = fmaf(whB[3], hM2, gB);
        gB = fmaf(wrB[0], R, gB);  gB = fmaf(wrB[1], RP, gB);
        gB = fmaf(wrB[2], RM, gB); gB = fmaf(wrB[3], RM2, gB);
        const float vA = fmaf(BA, __builtin_amdgcn_rcpf(1.f + __builtin_amdgcn_exp2f(gA)), AA);
        const float vB = __builtin_amdgcn_rcpf(1.f + __builtin_amdgcn_exp2f(gB));
        const float wA = dpp_f<CTL_SWAP>(vA);
        const float wB = dpp_f<CTL_SWAP>(vB);
        const float t1 = vA * wA;               // sigma(i)*tanh(g), same on both pair lanes
        const float fg = p ? wB : vB;
        const float og = p ? vB : wB;
        c = fmaf(fg, c, t1);
        const float e2 = __builtin_amdgcn_exp2f(2.8853900817779268f * c);
        const float th = fmaf(-2.f, __builtin_amdgcn_rcpf(1.f + e2), 1.f);
        h = og * th;
        wbase[((t + 31) & 31) & wmask] = h;     // real lanes: h1(t-1) -> ring slot
    };

    auto flush = [&](int f) {
        const int tt  = tix & 15;
        const int r   = tix >> 4;     // 0..11
        const int fci = r & 3;
        const int fu  = r >> 2;       // 0..2
        const int nn  = blockIdx.x * NCH + fci;
        const int bb  = (nn < BATCH) ? nn : nn - BATCH;
        const int cc  = (nn < BATCH) ? 0 : 3;
        const int t   = f * CHUNK + tt;
        const int slot = t & 31;
        const float2 bn = *reinterpret_cast<const float2*>(&lds_bn[2 * t]);
        float acc = 0.f;
        #pragma unroll
        for (int ee = 0; ee < 3; ++ee)
            acc += fmaxf(0.f, fmaf(lds_o[((ee * 4 + fci) * 3 + fu) * 34 + slot], bn.x, bn.y));
        out[((size_t)(bb * 6 + cc + fu)) * T_LEN + t] = acc * (1.f / 3.f);
    };

    // ================= schedule =================
    stage(0);
    __syncthreads();
    xproj();

    body(0, xpA[0], xpB[0]);
    if (L) { h = 0.f; c = 0.f; }      // discard layer-1's tau=-1 garbage
    #pragma unroll
    for (int tt = 1; tt < CHUNK; ++tt) body(tt, xpA[tt], xpB[tt]);

    #pragma unroll 1
    for (int cnk = 1; cnk < NCHUNK; ++cnk) {
        __syncthreads();
        stage(cnk);
        if (cnk >= 2) flush(cnk - 2);
        __syncthreads();
        xproj();
        const int tb = cnk * CHUNK;
        #pragma unroll
        for (int tt = 0; tt < CHUNK; ++tt) body(tb + tt, xpA[tt], xpB[tt]);
    }

    __syncthreads();
    flush(NCHUNK - 2);
    __syncthreads();
    body(T_LEN, xpA[0], xpB[0]);      // layer-1 completes step T-1
    __syncthreads();
    flush(NCHUNK - 1);
}

extern "C" void kernel_launch(void* const* d_in, const int* in_sizes, int n_in,
                              void* d_out, int out_size, void* d_ws, size_t ws_size,
                              hipStream_t stream) {
    (void)in_sizes; (void)n_in; (void)out_size; (void)d_ws; (void)ws_size;
    const float* x   = (const float*)d_in[0];
    const float* Wi0 = (const float*)d_in[1];
    const float* Wh0 = (const float*)d_in[2];
    const float* bi0 = (const float*)d_in[3];
    const float* bh0 = (const float*)d_in[4];
    const float* Wi1 = (const float*)d_in[5];
    const float* Wh1 = (const float*)d_in[6];
    const float* bi1 = (const float*)d_in[7];
    const float* bh1 = (const float*)d_in[8];
    const float* bng = (const float*)d_in[9];
    const float* bnb = (const float*)d_in[10];
    const float* bnm = (const float*)d_in[11];
    const float* bnv = (const float*)d_in[12];

    har_lstm_kernel<<<dim3(512), dim3(64, 3), 0, stream>>>(
        x, Wi0, Wh0, bi0, bh0, Wi1, Wh1, bi1, bh1, bng, bnb, bnm, bnv,
        (float*)d_out);
}

// Round 7
// 435.130 us; speedup vs baseline: 1.4776x; 1.1864x over previous
//
#include <hip/hip_runtime.h>

// HAR LSTM: r4 structure (8-lane chain-layer group, ds_bpermute cross-lane)
// + packed-f32 gate math (v_pk_fma_f32 via v2f) + register x-projections.
// 8-lane group = one (chain, encoder, layer): lane 2u+p computes gate rows
// {i_u,f_u} (p=0) or {g_u,o_u} (p=1); lanes 6,7 duplicate unit 0's pair.
// Per step: 6 ds_bpermute (own-h trio + partner-layer trio), ONE v2f 6-deep
// pk_fma chain for both gates (weights carry act pre-scales; partner weights
// zero on l0, x handled via per-chunk register projections), unified act
// exp2+rcp, DPP pair-swap, c/h update. Wave = 4 chains x 2 layers; block =
// 3 e-waves; grid 512 -> 1536 waves. 1-step layer skew; 32-slot h1 ring;
// BN+ReLU+mean flush with lag 2.

#define T_LEN 2048
#define BATCH 1024
#define CHUNK 16
#define NCHUNK 128
#define NCH 4

typedef float v2f __attribute__((ext_vector_type(2)));

__device__ __forceinline__ v2f splat(float x) { return (v2f){x, x}; }
__device__ __forceinline__ v2f vfma(v2f a, float b, v2f c) {
    return __builtin_elementwise_fma(a, splat(b), c);
}

__device__ __forceinline__ float dpp_swap(float v) {
    // quad_perm [1,0,3,2]: swap adjacent lane pairs
    int i = __float_as_int(v);
    i = __builtin_amdgcn_update_dpp(i, i, 0xB1, 0xF, 0xF, false);
    return __int_as_float(i);
}
__device__ __forceinline__ float bperm(int byteidx, float v) {
    return __int_as_float(__builtin_amdgcn_ds_bpermute(byteidx, __float_as_int(v)));
}

__launch_bounds__(192, 2)
__global__ void har_lstm_kernel(
    const float* __restrict__ x,
    const float* __restrict__ Wi0, const float* __restrict__ Wh0,
    const float* __restrict__ bi0, const float* __restrict__ bh0,
    const float* __restrict__ Wi1, const float* __restrict__ Wh1,
    const float* __restrict__ bi1, const float* __restrict__ bh1,
    const float* __restrict__ bng, const float* __restrict__ bnb,
    const float* __restrict__ bnm, const float* __restrict__ bnv,
    float* __restrict__ out)
{
    __shared__ __align__(16) float lds_x[NCH * 68];     // [ci][t*4+ch], stride 68
    __shared__ __align__(16) float lds_o[36 * 34];      // [(e*4+ci)*3+u][slot(32)+2pad]
    __shared__ __align__(16) float lds_bn[T_LEN * 2];   // [t][sc,sh]
    __shared__ float lds_dump[192];

    const int lane = threadIdx.x;       // 0..63
    const int e    = threadIdx.y;       // 0..2
    const int tix  = e * 64 + lane;

    const int grp = lane >> 3;          // 0..7
    const int L   = grp & 1;            // layer
    const int ci  = grp >> 1;           // chain in block 0..3
    const int sub = lane & 7;
    const int su  = (sub > 5) ? (sub - 6) : sub;   // lanes 6,7 dup unit 0
    const int u   = su >> 1;            // unit
    const int p   = su & 1;             // 0: rows {i,f} ; 1: rows {g,o}

    // ---- BN (scale, shift) table ----
    for (int idx = tix; idx < T_LEN; idx += 192) {
        const float sc = bng[idx] * rsqrtf(bnv[idx] + 1e-5f);
        lds_bn[2 * idx]     = sc;
        lds_bn[2 * idx + 1] = bnb[idx] - bnm[idx] * sc;
    }

    // ---- per-lane weights, act pre-scales folded; packed (A,B) pairs ----
    const float LOG2E = 1.4426950408889634f;
    const int   rowA = (p == 0) ? u : (6 + u);         // i_u or g_u
    const int   rowB = (p == 0) ? (3 + u) : (9 + u);   // f_u or o_u
    const float sA = (p == 0) ? -LOG2E : 2.0f * LOG2E;
    const float sB = -LOG2E;
    const float AA = (p == 0) ? 0.f : 1.f;             // vA = AA + BA*r0
    const float BA = (p == 0) ? 1.f : -2.f;
    const float* Wi = L ? Wi1 : Wi0;
    const float* Wh = L ? Wh1 : Wh0;
    const float* bi = L ? bi1 : bi0;
    const float* bh = L ? bh1 : bh0;

    v2f whv[3], wsv[3], wxv[3];
    #pragma unroll
    for (int k = 0; k < 3; ++k) {
        const float a = Wi[e * 36 + rowA * 3 + k];
        const float b = Wi[e * 36 + rowB * 3 + k];
        whv[k] = (v2f){sA * Wh[e * 36 + rowA * 3 + k], sB * Wh[e * 36 + rowB * 3 + k]};
        wsv[k] = L ? (v2f){sA * a, sB * b} : (v2f){0.f, 0.f};   // partner-h weights (l1)
        wxv[k] = L ? (v2f){0.f, 0.f} : (v2f){sA * a, sB * b};   // x weights (l0)
    }
    const v2f bsv = (v2f){sA * (bi[e * 12 + rowA] + bh[e * 12 + rowA]),
                          sB * (bi[e * 12 + rowB] + bh[e * 12 + rowB])};

    // ---- bpermute byte indices: own-group trio + partner-group trio ----
    const int gb = (lane & 0x38) << 2;   // group base lane * 4 bytes
    const int pb = gb ^ 32;              // partner group (lanes ^ 8)

    // ---- output routing ----
    const int n  = blockIdx.x * NCH + ci;
    const int b  = (n < BATCH) ? n : n - BATCH;
    const int cb = (n < BATCH) ? 0 : 3;
    const bool real = (L == 1) && (p == 0) && (sub < 6);
    float* wbase = real ? &lds_o[((e * 4 + ci) * 3 + u) * 34] : &lds_dump[tix];
    const int wmask = real ? -1 : 0;

    float h = 0.f, c = 0.f;
    v2f xp[CHUNK];

    auto stage = [&](int cnk) {
        if (tix < 48) {
            const int seg = tix & 3;
            const int r   = tix >> 2;    // 0..11
            const int ii  = r & 3;
            const int ch  = r >> 2;      // 0..2
            const int nn  = blockIdx.x * NCH + ii;
            const int bb  = (nn < BATCH) ? nn : nn - BATCH;
            const int cc  = (nn < BATCH) ? 0 : 3;
            const float4 v = *reinterpret_cast<const float4*>(
                x + ((size_t)(bb * 6 + cc + ch)) * T_LEN + cnk * CHUNK + seg * 4);
            float* d = &lds_x[ii * 68 + seg * 16 + ch];
            d[0] = v.x; d[4] = v.y; d[8] = v.z; d[12] = v.w;
        }
    };

    auto xproj = [&]() {
        #pragma unroll
        for (int tt = 0; tt < CHUNK; ++tt) {
            const float4 xv = *reinterpret_cast<const float4*>(&lds_x[ci * 68 + tt * 4]);
            xp[tt] = vfma(wxv[0], xv.x, vfma(wxv[1], xv.y, vfma(wxv[2], xv.z, bsv)));
        }
    };

    auto body = [&](int t, v2f xv) {
        const float h0r = bperm(gb,      h);
        const float h1r = bperm(gb + 8,  h);
        const float h2r = bperm(gb + 16, h);
        const float s0  = bperm(pb,      h);
        const float s1  = bperm(pb + 8,  h);
        const float s2  = bperm(pb + 16, h);
        v2f pre = xv;
        pre = vfma(whv[0], h0r, pre);
        pre = vfma(whv[1], h1r, pre);
        pre = vfma(whv[2], h2r, pre);
        pre = vfma(wsv[0], s0,  pre);
        pre = vfma(wsv[1], s1,  pre);
        pre = vfma(wsv[2], s2,  pre);
        const float r0 = __builtin_amdgcn_rcpf(1.f + __builtin_amdgcn_exp2f(pre.x));
        const float r1 = __builtin_amdgcn_rcpf(1.f + __builtin_amdgcn_exp2f(pre.y));
        const float vA = fmaf(BA, r0, AA);     // p0: sigma(i) ; p1: tanh(g)
        const float vB = r1;                   // p0: sigma(f) ; p1: sigma(o)
        const float wA = dpp_swap(vA);
        const float wB = dpp_swap(vB);
        const float t1 = vA * wA;              // sigma(i)*tanh(g) on both pair lanes
        const float fg = p ? wB : vB;
        const float og = p ? vB : wB;
        c = fmaf(fg, c, t1);
        const float e2 = __builtin_amdgcn_exp2f(2.8853900817779268f * c);
        const float th = fmaf(-2.f, __builtin_amdgcn_rcpf(1.f + e2), 1.f);
        h = og * th;
        wbase[((t + 31) & 31) & wmask] = h;    // real lanes: h1(t-1) -> ring slot
    };

    auto flush = [&](int f) {
        const int tt  = tix & 15;
        const int r   = tix >> 4;     // 0..11
        const int fci = r & 3;
        const int fu  = r >> 2;       // 0..2
        const int nn  = blockIdx.x * NCH + fci;
        const int bb  = (nn < BATCH) ? nn : nn - BATCH;
        const int cc  = (nn < BATCH) ? 0 : 3;
        const int t   = f * CHUNK + tt;
        const int slot = t & 31;
        const float2 bn = *reinterpret_cast<const float2*>(&lds_bn[2 * t]);
        float acc = 0.f;
        #pragma unroll
        for (int ee = 0; ee < 3; ++ee)
            acc += fmaxf(0.f, fmaf(lds_o[((ee * 4 + fci) * 3 + fu) * 34 + slot], bn.x, bn.y));
        out[((size_t)(bb * 6 + cc + fu)) * T_LEN + t] = acc * (1.f / 3.f);
    };

    // ================= schedule =================
    stage(0);
    __syncthreads();
    xproj();

    body(0, xp[0]);
    if (L) { h = 0.f; c = 0.f; }      // discard layer-1's tau=-1 garbage
    #pragma unroll
    for (int tt = 1; tt < CHUNK; ++tt) body(tt, xp[tt]);

    #pragma unroll 1
    for (int cnk = 1; cnk < NCHUNK; ++cnk) {
        __syncthreads();
        stage(cnk);
        if (cnk >= 2) flush(cnk - 2);
        __syncthreads();
        xproj();
        const int tb = cnk * CHUNK;
        #pragma unroll
        for (int tt = 0; tt < CHUNK; ++tt) body(tb + tt, xp[tt]);
    }

    __syncthreads();
    flush(NCHUNK - 2);
    __syncthreads();
    body(T_LEN, bsv);                 // layer-1 completes step T-1 (x side unused)
    __syncthreads();
    flush(NCHUNK - 1);
}

extern "C" void kernel_launch(void* const* d_in, const int* in_sizes, int n_in,
                              void* d_out, int out_size, void* d_ws, size_t ws_size,
                              hipStream_t stream) {
    (void)in_sizes; (void)n_in; (void)out_size; (void)d_ws; (void)ws_size;
    const float* x   = (const float*)d_in[0];
    const float* Wi0 = (const float*)d_in[1];
    const float* Wh0 = (const float*)d_in[2];
    const float* bi0 = (const float*)d_in[3];
    const float* bh0 = (const float*)d_in[4];
    const float* Wi1 = (const float*)d_in[5];
    const float* Wh1 = (const float*)d_in[6];
    const float* bi1 = (const float*)d_in[7];
    const float* bh1 = (const float*)d_in[8];
    const float* bng = (const float*)d_in[9];
    const float* bnb = (const float*)d_in[10];
    const float* bnm = (const float*)d_in[11];
    const float* bnv = (const float*)d_in[12];

    har_lstm_kernel<<<dim3(512), dim3(64, 3), 0, stream>>>(
        x, Wi0, Wh0, bi0, bh0, Wi1, Wh1, bi1, bh1, bng, bnb, bnm, bnv,
        (float*)d_out);
}